// Round 3
// baseline (79.315 us; speedup 1.0000x reference)
//
#include <hip/hip_runtime.h>
#include <math.h>

// GCN actor collapses: complete graph + self loops + unit edge weights
// => deg==32, norm==1/32 => GCN aggregation == per-sample mean; after layer 1
// all 32 nodes identical => layer-2 aggregation is identity. Whole net:
// per-sample MLP 14 -> 128 -> 128 -> 128 -> 4, then tile outputs over 32 nodes.
//
// R3: one sample per WAVE, one wave per block, ZERO barriers. 1024 blocks x 64
// threads = 4 independent waves/CU; wave-synchronous LDS for activation
// broadcast; shfl butterflies for mean + head reduction.

constexpr int NODES = 32;
constexpr int OBSD  = 16;
constexpr int H     = 128;

__global__ __launch_bounds__(64, 1) void gcn_actor_wave(
    const float* __restrict__ obs,
    const float* __restrict__ W1,  const float* __restrict__ b1,
    const float* __restrict__ W2,  const float* __restrict__ b2,
    const float* __restrict__ Wm1, const float* __restrict__ bm1,
    const float* __restrict__ Wm2, const float* __restrict__ bm2,
    float* __restrict__ out, int bs)
{
    const int l  = threadIdx.x;        // lane [0,64)
    const int s  = blockIdx.x;         // sample
    const int n2 = 2 * l;              // this lane's neuron pair

    __shared__ float sm[16];           // per-sample column means
    __shared__ float sx[H];            // activation ping
    __shared__ float sy[H];            // activation pong

    // ---- obs column means over 32 nodes (16 cols; we use 2..15) ----
    // float4 f of the 512-float sample covers node f>>2, cols 4*(f&3)..+3.
    {
        const float4* g = reinterpret_cast<const float4*>(obs) + (size_t)s * 128;
        const float4 a = g[l];
        const float4 c = g[l + 64];
        float4 p = make_float4(a.x + c.x, a.y + c.y, a.z + c.z, a.w + c.w);
        #pragma unroll
        for (int m = 4; m <= 32; m <<= 1) {      // reduce over node bits 2..5
            p.x += __shfl_xor(p.x, m, 64);
            p.y += __shfl_xor(p.y, m, 64);
            p.z += __shfl_xor(p.z, m, 64);
            p.w += __shfl_xor(p.w, m, 64);
        }
        if (l < 4) {                             // lane c holds colgroup c sums
            const float sc = 1.0f / 32.0f;
            reinterpret_cast<float4*>(sm)[l] =
                make_float4(p.x * sc, p.y * sc, p.z * sc, p.w * sc);
        }
        // wave-synchronous: DS ops in a wave are in-order; no barrier needed.
    }

    // ---- L1: mean(cols 2..15) @ W1 + b1, relu -> sx ----
    {
        float2 acc = *reinterpret_cast<const float2*>(b1 + n2);
        #pragma unroll
        for (int k = 0; k < 14; ++k) {
            const float2 w = *reinterpret_cast<const float2*>(W1 + k * H + n2);
            const float mk = sm[2 + k];          // LDS broadcast
            acc.x = fmaf(w.x, mk, acc.x);
            acc.y = fmaf(w.y, mk, acc.y);
        }
        *reinterpret_cast<float2*>(sx + n2) =
            make_float2(fmaxf(acc.x, 0.f), fmaxf(acc.y, 0.f));
    }

    // ---- dense 128->128 layer: xout = relu(xin @ W + b); returns lane pair ----
    auto layer = [&](const float* __restrict__ W, const float* __restrict__ bias,
                     const float* xin, float* xout) -> float2 {
        const float2 bb = *reinterpret_cast<const float2*>(bias + n2);
        // 4 independent FMA chains (ax0/ax1/ay0/ay1) for dep-latency ILP
        float ax0 = bb.x, ax1 = 0.f, ay0 = bb.y, ay1 = 0.f;
        #pragma unroll
        for (int k0 = 0; k0 < H; k0 += 4) {
            const float4  xv = *reinterpret_cast<const float4*>(xin + k0); // b128 broadcast
            const float2 w0 = *reinterpret_cast<const float2*>(W + (k0 + 0) * H + n2);
            const float2 w1 = *reinterpret_cast<const float2*>(W + (k0 + 1) * H + n2);
            const float2 w2 = *reinterpret_cast<const float2*>(W + (k0 + 2) * H + n2);
            const float2 w3 = *reinterpret_cast<const float2*>(W + (k0 + 3) * H + n2);
            ax0 = fmaf(w0.x, xv.x, fmaf(w1.x, xv.y, ax0));
            ax1 = fmaf(w2.x, xv.z, fmaf(w3.x, xv.w, ax1));
            ay0 = fmaf(w0.y, xv.x, fmaf(w1.y, xv.y, ay0));
            ay1 = fmaf(w2.y, xv.z, fmaf(w3.y, xv.w, ay1));
        }
        const float rx = fmaxf(ax0 + ax1, 0.f);
        const float ry = fmaxf(ay0 + ay1, 0.f);
        *reinterpret_cast<float2*>(xout + n2) = make_float2(rx, ry);
        return make_float2(rx, ry);
    };

    layer(W2, b2, sx, sy);                     // L2
    const float2 mv = layer(Wm1, bm1, sy, sx); // L3: m kept in regs too

    // ---- head: o[c] = m @ Wm2[:,c] + bm2[c]; 64-lane butterfly ----
    float4 o;
    {
        const float4 wa = *reinterpret_cast<const float4*>(Wm2 + 8 * l);      // row 2l
        const float4 wb = *reinterpret_cast<const float4*>(Wm2 + 8 * l + 4);  // row 2l+1
        o.x = fmaf(mv.x, wa.x, mv.y * wb.x);
        o.y = fmaf(mv.x, wa.y, mv.y * wb.y);
        o.z = fmaf(mv.x, wa.z, mv.y * wb.z);
        o.w = fmaf(mv.x, wa.w, mv.y * wb.w);
        #pragma unroll
        for (int m = 1; m < 64; m <<= 1) {
            o.x += __shfl_xor(o.x, m, 64);
            o.y += __shfl_xor(o.y, m, 64);
            o.z += __shfl_xor(o.z, m, 64);
            o.w += __shfl_xor(o.w, m, 64);
        }
        const float4 bb = *reinterpret_cast<const float4*>(bm2);
        o.x += bb.x;
        o.y += bb.y;
        // squash: std = exp(LOG_STD_MIN + 0.5*range*(tanh(ls)+1)) = exp(-1.5 + 3.5*tanh)
        o.z = expf(-1.5f + 3.5f * tanhf(o.z + bb.z));
        o.w = expf(-1.5f + 3.5f * tanhf(o.w + bb.w));
    }

    // ---- write out (2, bs, 64): sample's 64 = (v0,v1) x 32 nodes ----
    if (l < 32) {
        const int half = l >> 4;               // 0 = mu, 1 = std
        const int t    = l & 15;               // float4 idx in 64-float region
        const float v0 = half ? o.z : o.x;
        const float v1 = half ? o.w : o.y;
        float4* dst = reinterpret_cast<float4*>(out + (size_t)half * bs * 64 + (size_t)s * 64);
        dst[t] = make_float4(v0, v1, v0, v1);
    }
}

extern "C" void kernel_launch(void* const* d_in, const int* in_sizes, int n_in,
                              void* d_out, int out_size, void* d_ws, size_t ws_size,
                              hipStream_t stream) {
    const float* obs = (const float*)d_in[0];
    const float* W1  = (const float*)d_in[1];
    const float* b1  = (const float*)d_in[2];
    const float* W2  = (const float*)d_in[3];
    const float* b2  = (const float*)d_in[4];
    const float* Wm1 = (const float*)d_in[5];
    const float* bm1 = (const float*)d_in[6];
    const float* Wm2 = (const float*)d_in[7];
    const float* bm2 = (const float*)d_in[8];
    float* out = (float*)d_out;

    const int bs = in_sizes[0] / (NODES * OBSD);   // 1024 samples
    gcn_actor_wave<<<bs, 64, 0, stream>>>(obs, W1, b1, W2, b2, Wm1, bm1, Wm2, bm2, out, bs);
}

// Round 4
// 73.642 us; speedup vs baseline: 1.0770x; 1.0770x over previous
//
#include <hip/hip_runtime.h>
#include <math.h>

// GCN actor collapses: complete graph + self loops + unit edge weights
// => deg==32, norm==1/32 => GCN aggregation == per-sample mean; after layer 1
// all 32 nodes identical => layer-2 aggregation is identity. Whole net:
// per-sample MLP 14 -> 128 -> 128 -> 128 -> 4, outputs tiled over 32 nodes.
//
// R4 = R2 skeleton (512 thr, 4 samples/block, K-split-4) with:
//  - ALL weights prefetched to registers at kernel top (latency overlaps obs
//    stage; L2 is poison-flushed every iteration so loads are cold)
//  - obs means via per-wave shfl butterfly (no LDS staging, kills 2 barriers)
//  - L1 computed redundantly across q-groups (kills a partial-reduce barrier)

constexpr int NODES = 32;
constexpr int OBSD  = 16;
constexpr int H     = 128;
constexpr int SPB   = 4;
constexpr int TPB   = 512;   // n = tid&127 (neuron), q = tid>>7 (k-quarter)

__global__ __launch_bounds__(TPB, 2) void gcn_actor(
    const float* __restrict__ obs,
    const float* __restrict__ W1,  const float* __restrict__ b1,
    const float* __restrict__ W2,  const float* __restrict__ b2,
    const float* __restrict__ Wm1, const float* __restrict__ bm1,
    const float* __restrict__ Wm2, const float* __restrict__ bm2,
    float* __restrict__ out, int bs)
{
    const int tid = threadIdx.x;
    const int n   = tid & (H - 1);
    const int q   = tid >> 7;
    const int s0  = blockIdx.x * SPB;
    const int p5  = tid & 31;          // head: k-chunk
    const int c5  = (tid >> 5) & 3;    // head: output column
    const int s5  = tid >> 7;          // head: sample

    __shared__ float s_mean[SPB][16];
    __shared__ float s_part[4][SPB][H];
    __shared__ float s_x[SPB][H];
    __shared__ float s_y[SPB][H];
    __shared__ float s_o[SPB][4];

    // ---- prefetch all weights/biases into registers (issued first; their
    // latency overlaps the obs stage; everything drains at the first barrier) ----
    float w1r[14], w2r[32], wm1r[32], wm2r[4];
    #pragma unroll
    for (int k = 0; k < 14; ++k) w1r[k] = W1[k * H + n];
    #pragma unroll
    for (int i = 0; i < 32; ++i) w2r[i] = W2[(q * 32 + i) * H + n];
    #pragma unroll
    for (int i = 0; i < 32; ++i) wm1r[i] = Wm1[(q * 32 + i) * H + n];
    #pragma unroll
    for (int j = 0; j < 4; ++j) wm2r[j] = Wm2[(p5 * 4 + j) * 4 + c5];
    const float b1v = b1[n], b2v = b2[n], bm1v = bm1[n], bm2v = bm2[c5];

    // ---- obs column means: wave w (w<4) butterfly-reduces sample w ----
    {
        const int w = tid >> 6, l = tid & 63;
        if (w < SPB) {
            const float4* g = reinterpret_cast<const float4*>(obs) + (size_t)(s0 + w) * 128;
            const float4 a = g[l];          // nodes 0..15
            const float4 c = g[l + 64];     // nodes 16..31
            float4 p = make_float4(a.x + c.x, a.y + c.y, a.z + c.z, a.w + c.w);
            #pragma unroll
            for (int m = 4; m <= 32; m <<= 1) {   // reduce node bits (lane bits 2..5)
                p.x += __shfl_xor(p.x, m, 64);
                p.y += __shfl_xor(p.y, m, 64);
                p.z += __shfl_xor(p.z, m, 64);
                p.w += __shfl_xor(p.w, m, 64);
            }
            if (l < 4) {                          // lane l holds colgroup l sums
                const float sc = 1.0f / 32.0f;
                reinterpret_cast<float4*>(&s_mean[w][0])[l] =
                    make_float4(p.x * sc, p.y * sc, p.z * sc, p.w * sc);
            }
        }
    }
    __syncthreads();

    // ---- L1: mean(cols 2..15) @ W1 + b1, relu (redundant across q) ----
    {
        float acc[SPB];
        #pragma unroll
        for (int s = 0; s < SPB; ++s) acc[s] = b1v;
        #pragma unroll
        for (int k = 0; k < 14; ++k) {
            #pragma unroll
            for (int s = 0; s < SPB; ++s) acc[s] = fmaf(w1r[k], s_mean[s][2 + k], acc[s]);
        }
        if (q == 0) {
            #pragma unroll
            for (int s = 0; s < SPB; ++s) s_x[s][n] = fmaxf(acc[s], 0.f);
        }
    }
    __syncthreads();

    // ---- L2: s_x @ W2 (K-split-4, weights already in regs) ----
    {
        float acc[SPB] = {0.f, 0.f, 0.f, 0.f};
        #pragma unroll
        for (int i = 0; i < 8; ++i) {
            #pragma unroll
            for (int s = 0; s < SPB; ++s) {
                const float4 xv = *reinterpret_cast<const float4*>(&s_x[s][q * 32 + i * 4]);
                acc[s] = fmaf(w2r[i*4+3], xv.w, fmaf(w2r[i*4+2], xv.z,
                         fmaf(w2r[i*4+1], xv.y, fmaf(w2r[i*4+0], xv.x, acc[s]))));
            }
        }
        #pragma unroll
        for (int s = 0; s < SPB; ++s) s_part[q][s][n] = acc[s];
    }
    __syncthreads();
    {
        float v = b2v;
        #pragma unroll
        for (int qq = 0; qq < 4; ++qq) v += s_part[qq][s5][n];
        s_y[s5][n] = fmaxf(v, 0.f);
    }
    __syncthreads();

    // ---- L3: s_y @ Wm1 ----
    {
        float acc[SPB] = {0.f, 0.f, 0.f, 0.f};
        #pragma unroll
        for (int i = 0; i < 8; ++i) {
            #pragma unroll
            for (int s = 0; s < SPB; ++s) {
                const float4 xv = *reinterpret_cast<const float4*>(&s_y[s][q * 32 + i * 4]);
                acc[s] = fmaf(wm1r[i*4+3], xv.w, fmaf(wm1r[i*4+2], xv.z,
                         fmaf(wm1r[i*4+1], xv.y, fmaf(wm1r[i*4+0], xv.x, acc[s]))));
            }
        }
        #pragma unroll
        for (int s = 0; s < SPB; ++s) s_part[q][s][n] = acc[s];
    }
    __syncthreads();
    {
        float v = bm1v;
        #pragma unroll
        for (int qq = 0; qq < 4; ++qq) v += s_part[qq][s5][n];
        s_x[s5][n] = fmaxf(v, 0.f);   // m
    }
    __syncthreads();

    // ---- head: o[s][c] = m @ Wm2[:,c] + bm2[c]; 32-lane shfl reduce ----
    {
        const float4 mv = reinterpret_cast<const float4*>(&s_x[s5][0])[p5];
        float acc =      mv.x * wm2r[0];
        acc = fmaf(mv.y, wm2r[1], acc);
        acc = fmaf(mv.z, wm2r[2], acc);
        acc = fmaf(mv.w, wm2r[3], acc);
        #pragma unroll
        for (int m = 16; m; m >>= 1) acc += __shfl_xor(acc, m, 64);  // bits 0..4 = p5
        if (p5 == 0) {
            float v = acc + bm2v;
            if (c5 >= 2) v = expf(-1.5f + 3.5f * tanhf(v));  // exp(-5 + 3.5*(tanh+1))
            s_o[s5][c5] = v;
        }
    }
    __syncthreads();

    // ---- write out (2, bs, 64): sample's 64 = (v0,v1) x 32 nodes ----
    if (tid < 128) {
        const int half = tid >> 6;
        const int t    = tid & 63;
        const int s    = t >> 4;
        const float v0 = s_o[s][half * 2 + 0];
        const float v1 = s_o[s][half * 2 + 1];
        float4* dst = reinterpret_cast<float4*>(out + (size_t)half * bs * 64 + (size_t)s0 * 64);
        dst[t] = make_float4(v0, v1, v0, v1);
    }
}

extern "C" void kernel_launch(void* const* d_in, const int* in_sizes, int n_in,
                              void* d_out, int out_size, void* d_ws, size_t ws_size,
                              hipStream_t stream) {
    const float* obs = (const float*)d_in[0];
    const float* W1  = (const float*)d_in[1];
    const float* b1  = (const float*)d_in[2];
    const float* W2  = (const float*)d_in[3];
    const float* b2  = (const float*)d_in[4];
    const float* Wm1 = (const float*)d_in[5];
    const float* bm1 = (const float*)d_in[6];
    const float* Wm2 = (const float*)d_in[7];
    const float* bm2 = (const float*)d_in[8];
    float* out = (float*)d_out;

    const int bs   = in_sizes[0] / (NODES * OBSD);   // 1024
    const int grid = bs / SPB;                       // 256 blocks, 1/CU

    gcn_actor<<<grid, TPB, 0, stream>>>(obs, W1, b1, W2, b2, Wm1, bm1, Wm2, bm2, out, bs);
}